// Round 1
// baseline (230.606 us; speedup 1.0000x reference)
//
#include <hip/hip_runtime.h>
#include <hip/hip_bf16.h>
#include <hip/hip_fp16.h>
#include <math.h>

// Problem: h = z @ W + b  (z [N,256] fp32, W [256,256] fp32, b [256])
//          out[e] = sigmoid(dot(h[src[e]], h[dst[e]]))  for E edges
// N = 100000, E = 300000, D = 256.
//
// R13: barrier-free GEMM. The per-kb __syncthreads drained vmcnt(0) for all
// waves (compiler semantics), serializing the block on the A-prefetch HBM
// latency -> MfmaUtil 7.6%, 62us. B (g_Wf, 128KB) is L2-resident and its
// fragment read is a perfectly-coalesced 1KB/wave global load, so B now
// goes global->VGPR double-buffered (no LDS, no barriers, no 8-way LDS
// bank conflicts). A is prefetched depth-2 (3 reg buffers). kb fully
// unrolled -> all buffer indices static (no scratch). LDS kept only for
// the wave-private store epilogue (same-wave ordering, no sync).
// Block 256 thr / BM=64, grid 1563. Edge kernel unchanged.

#define D_DIM 256
#define BM 64

typedef __attribute__((ext_vector_type(8))) _Float16 half8;
typedef __attribute__((ext_vector_type(4))) float f32x4;

__device__ half8 g_Wf[8 * 256 * 4];   // [kb][n][qd] -> 16B fp16 frag, 128 KB

// 8192 threads: t -> (kb, qd, n), n fastest => coalesced row reads of W.
__global__ __launch_bounds__(256) void pack_w_kernel(const float* __restrict__ W) {
  int t = blockIdx.x * 256 + threadIdx.x;   // 0..8191
  int kb = t >> 10;
  int qd = (t >> 8) & 3;
  int n  = t & 255;
  half8 o;
#pragma unroll
  for (int j = 0; j < 8; j++)
    o[j] = (_Float16)W[(size_t)(kb * 32 + qd * 8 + j) * D_DIM + n];
  g_Wf[(kb * 256 + n) * 4 + qd] = o;
}

__global__ __launch_bounds__(256) void gemm_mfma_kernel(
    const float* __restrict__ z, const float* __restrict__ b,
    __half* __restrict__ h, int nrows) {
  // LDS: epilogue only — per-wave 16x136-half tile (4352B), 4 waves.
  __shared__ char smem[4 * 4352];
  const int tid = threadIdx.x;
  const int lane = tid & 63;
  const int wv = tid >> 6;          // 0..3
  const int mg = wv >> 1;           // m-group: rows mg*32 .. +31 (2 frags)
  const int nh = wv & 1;            // n-half: cols nh*128 .. +127
  const int fr = lane & 15;
  const int qd = lane >> 4;
  const int row0 = blockIdx.x * BM + mg * 32;

  f32x4 acc[2][8];
#pragma unroll
  for (int i = 0; i < 2; i++)
#pragma unroll
    for (int j = 0; j < 8; j++) acc[i][j] = (f32x4)0.f;

  const float* zrow[2];
#pragma unroll
  for (int fm = 0; fm < 2; fm++) {
    int r = row0 + fm * 16 + fr;
    r = r < nrows ? r : (nrows - 1);
    zrow[fm] = z + (size_t)r * D_DIM + qd * 8;
  }

  const half8* gw = g_Wf;
  // per-lane B fragment base (half8 units); kb*1024 + fn*64 folded as
  // compile-time immediates after full unroll.
  const int bbase = ((nh * 128 + fr) << 2) + qd;

  // A: 3 buffers (depth-2 prefetch). B: 2 buffers (depth-1, L2-latency).
  float4 a0[3][2], a1[3][2];
  half8 bf[2][8];

#pragma unroll
  for (int s = 0; s < 2; s++)
#pragma unroll
    for (int fm = 0; fm < 2; fm++) {
      const float* p = zrow[fm] + s * 32;
      a0[s][fm] = *(const float4*)(p);
      a1[s][fm] = *(const float4*)(p + 4);
    }
#pragma unroll
  for (int fn = 0; fn < 8; fn++) bf[0][fn] = gw[fn * 64 + bbase];

#pragma unroll
  for (int kb = 0; kb < 8; kb++) {
    const int cA = kb % 3;            // static after unroll
    const int pA = (kb + 2) % 3;
    const int cB = kb & 1;
    const int nB = cB ^ 1;

    // prefetch A for kb+2 (HBM/L3, ~2 iterations of latency cover)
    if (kb < 6) {
#pragma unroll
      for (int fm = 0; fm < 2; fm++) {
        const float* p = zrow[fm] + (kb + 2) * 32;
        a0[pA][fm] = *(const float4*)(p);
        a1[pA][fm] = *(const float4*)(p + 4);
      }
    }
    // prefetch B for kb+1 (L2-resident, coalesced 1KB/wave per fn)
    if (kb < 7) {
#pragma unroll
      for (int fn = 0; fn < 8; fn++)
        bf[nB][fn] = gw[(kb + 1) * 1024 + fn * 64 + bbase];
    }

    // convert current A fp32 -> fp16 frags (16 v_cvt)
    half8 af[2];
#pragma unroll
    for (int fm = 0; fm < 2; fm++) {
      af[fm][0] = (_Float16)a0[cA][fm].x; af[fm][1] = (_Float16)a0[cA][fm].y;
      af[fm][2] = (_Float16)a0[cA][fm].z; af[fm][3] = (_Float16)a0[cA][fm].w;
      af[fm][4] = (_Float16)a1[cA][fm].x; af[fm][5] = (_Float16)a1[cA][fm].y;
      af[fm][6] = (_Float16)a1[cA][fm].z; af[fm][7] = (_Float16)a1[cA][fm].w;
    }

#pragma unroll
    for (int fn = 0; fn < 8; fn++)
#pragma unroll
      for (int fm = 0; fm < 2; fm++)
        acc[fm][fn] = __builtin_amdgcn_mfma_f32_16x16x32_f16(af[fm], bf[cB][fn], acc[fm][fn], 0, 0, 0);
  }

  // Epilogue: per-wave 16x136-half LDS tile (272B stride: 2-way max, free),
  // reused for both m-frags (same-wave LDS ordering; verified R4-R12).
  __half* et = (__half*)(smem + wv * 4352);
  float bias[8];
#pragma unroll
  for (int fn = 0; fn < 8; fn++) bias[fn] = b[nh * 128 + fn * 16 + fr];

#pragma unroll
  for (int fm = 0; fm < 2; fm++) {
#pragma unroll
    for (int fn = 0; fn < 8; fn++)
#pragma unroll
      for (int r = 0; r < 4; r++)
        et[(qd * 4 + r) * 136 + fn * 16 + fr] = __float2half(acc[fm][fn][r] + bias[fn]);
#pragma unroll
    for (int p = 0; p < 4; p++) {
      int idx = p * 64 + lane;        // 0..255
      int rr = idx >> 4;              // 0..15
      int cc = idx & 15;              // 16B chunk within 256B row-half
      float4 v = *(const float4*)(et + rr * 136 + cc * 8);
      int row = row0 + fm * 16 + rr;
      if (row < nrows)
        *(float4*)(h + (size_t)row * D_DIM + nh * 128 + cc * 8) = v;
    }
  }
}

// 1 wave per 8 edges; per edge ONE 1KB load instr: lanes 0-31 cover the
// 512B src row, lanes 32-63 the dst row. Pair via shfl_xor(32), butterfly.
__global__ __launch_bounds__(256) void edge_dot_kernel(
    const int* __restrict__ ei, const __half* __restrict__ h,
    float* __restrict__ out, int E) {
  int wid = (blockIdx.x * blockDim.x + threadIdx.x) >> 6;
  int lane = threadIdx.x & 63;
  int ebase = wid * 8;
  if (ebase >= E) return;
  const int half = lane >> 5;      // 0=src row, 1=dst row
  const int off = lane & 31;       // float4 chunk within the 512B row

  float4 v[8];
#pragma unroll
  for (int q = 0; q < 8; q++) {
    int e = ebase + q;
    e = e < E ? e : (E - 1);
    int node = half ? ei[E + e] : ei[e];   // uniform per 32-lane half
    v[q] = *(const float4*)((const __half*)h + (size_t)node * D_DIM + off * 8);
  }

  float res = 0.f;
#pragma unroll
  for (int q = 0; q < 8; q++) {
    float4 w;
    w.x = __shfl_xor(v[q].x, 32);
    w.y = __shfl_xor(v[q].y, 32);
    w.z = __shfl_xor(v[q].z, 32);
    w.w = __shfl_xor(v[q].w, 32);
    const __half2* a2 = (const __half2*)&v[q];
    const __half2* b2 = (const __half2*)&w;
    float part = 0.f;
#pragma unroll
    for (int j = 0; j < 4; j++) {
      float2 fa = __half22float2(a2[j]);
      float2 fb = __half22float2(b2[j]);
      part += fa.x * fb.x + fa.y * fb.y;
    }
#pragma unroll
    for (int m = 1; m <= 16; m <<= 1) part += __shfl_xor(part, m);
    res = (lane == q) ? part : res;    // lanes 0..7 collect the 8 results
  }
  if (lane < 8) {
    int e = ebase + lane;
    if (e < E) out[e] = 1.0f / (1.0f + __expf(-res));
  }
}

extern "C" void kernel_launch(void* const* d_in, const int* in_sizes, int n_in,
                              void* d_out, int out_size, void* d_ws, size_t ws_size,
                              hipStream_t stream) {
  const float* z  = (const float*)d_in[0];
  const int*   ei = (const int*)d_in[1];
  const float* W  = (const float*)d_in[2];
  const float* b  = (const float*)d_in[3];
  float* out = (float*)d_out;
  __half* h  = (__half*)d_ws;   // 100000*256*2 = 51.2 MB scratch

  const int nnodes = in_sizes[0] / D_DIM;
  const int E = in_sizes[1] / 2;

  pack_w_kernel<<<32, 256, 0, stream>>>(W);

  dim3 grid_gemm((nnodes + BM - 1) / BM);
  gemm_mfma_kernel<<<grid_gemm, 256, 0, stream>>>(z, b, h, nnodes);

  int waves = (E + 7) / 8;                        // 1 wave per 8 edges
  dim3 grid_edge(((size_t)waves * 64 + 255) / 256);
  edge_dot_kernel<<<grid_edge, 256, 0, stream>>>(ei, h, out, E);
}

// Round 2
// 219.705 us; speedup vs baseline: 1.0496x; 1.0496x over previous
//
#include <hip/hip_runtime.h>
#include <hip/hip_bf16.h>
#include <hip/hip_fp16.h>
#include <math.h>

// Problem: h = z @ W + b  (z [N,256] fp32, W [256,256] fp32, b [256])
//          out[e] = sigmoid(dot(h[src[e]], h[dst[e]]))  for E edges
// N = 100000, E = 300000, D = 256.
//
// R14: R12 structure (BM=128, 512 thr, 16KB x2 LDS dbuf for B) with the
// barrier drain fixed: per-kb __syncthreads() (which emits s_waitcnt
// vmcnt(0) -> drains the A prefetch, serializing all waves on HBM
// latency) is replaced by counted `s_waitcnt vmcnt(4)` + raw s_barrier.
// The 2 global_load_lds stage ops are issued FIRST (pinned by an empty
// asm fence) so vmcnt(4) provably retires them while the 4 A-prefetch
// loads stay in flight ACROSS the barrier (T4 counted-vmcnt lever).
// A is double-buffered in regs (full unroll -> static indices) and
// prefetched at iteration start. R13 lesson: with no barriers at all the
// compiler sinks loads to their uses (VGPR=80) and kills the pipeline.

#define D_DIM 256
#define BM 128

typedef __attribute__((ext_vector_type(8))) _Float16 half8;
typedef __attribute__((ext_vector_type(4))) float f32x4;

__device__ half8 g_Wf[8 * 256 * 4];   // [kb][n][qd] -> 16B fp16 frag, 128 KB

// 8192 threads: t -> (kb, qd, n), n fastest => coalesced row reads of W.
__global__ __launch_bounds__(256) void pack_w_kernel(const float* __restrict__ W) {
  int t = blockIdx.x * 256 + threadIdx.x;   // 0..8191
  int kb = t >> 10;
  int qd = (t >> 8) & 3;
  int n  = t & 255;
  half8 o;
#pragma unroll
  for (int j = 0; j < 8; j++)
    o[j] = (_Float16)W[(size_t)(kb * 32 + qd * 8 + j) * D_DIM + n];
  g_Wf[(kb * 256 + n) * 4 + qd] = o;
}

// Stage one kb's 16 KB of B frags into an LDS buffer; 8 waves x 2 KB.
__device__ inline void stage_b(int kb, char* buf, int wv, int lane) {
  const char* gsrc = (const char*)g_Wf + (size_t)kb * 16384 + wv * 2048;
  char* ldst = buf + wv * 2048;
#pragma unroll
  for (int i = 0; i < 2; i++) {
    __builtin_amdgcn_global_load_lds(
        (const __attribute__((address_space(1))) void*)(gsrc + i * 1024 + lane * 16),
        (__attribute__((address_space(3))) void*)(ldst + i * 1024),
        16, 0, 0);
  }
}

__global__ __launch_bounds__(512, 4) void gemm_mfma_kernel(
    const float* __restrict__ z, const float* __restrict__ b,
    __half* __restrict__ h, int nrows) {
  // 2x16KB B double-buffer; epilogue tiles (8x4352B=34816B) alias the lot.
  __shared__ char smem[34816];
  const int tid = threadIdx.x;
  const int lane = tid & 63;
  const int wv = tid >> 6;          // 0..7
  const int mg = wv >> 1;           // m-group: rows mg*32 .. +31 (2 frags)
  const int nh = wv & 1;            // n-half: cols nh*128 .. +127
  const int fr = lane & 15;
  const int qd = lane >> 4;
  const int row0 = blockIdx.x * BM + mg * 32;

  f32x4 acc[2][8];
#pragma unroll
  for (int i = 0; i < 2; i++)
#pragma unroll
    for (int j = 0; j < 8; j++) acc[i][j] = (f32x4)0.f;

  const float* zrow[2];
#pragma unroll
  for (int fm = 0; fm < 2; fm++) {
    int r = row0 + fm * 16 + fr;
    r = r < nrows ? r : (nrows - 1);
    zrow[fm] = z + (size_t)r * D_DIM + qd * 8;
  }

  // A double-buffer in regs; indices static after full unroll.
  float4 a0[2][2], a1[2][2];

  // Prologue: stage B(0) FIRST (oldest vmem), fence, then A(0) loads.
  // vmcnt(4) retires the 2 stage ops; the 4 A loads cross the barrier.
  stage_b(0, smem, wv, lane);
  asm volatile("" ::: "memory");    // pin: stage issues before A loads
#pragma unroll
  for (int fm = 0; fm < 2; fm++) {
    a0[0][fm] = *(const float4*)(zrow[fm]);
    a1[0][fm] = *(const float4*)(zrow[fm] + 4);
  }
  asm volatile("s_waitcnt vmcnt(4)" ::: "memory");
  __builtin_amdgcn_s_barrier();

#pragma unroll
  for (int kb = 0; kb < 8; kb++) {
    const int cA = kb & 1;          // static after unroll
    const int nA = cA ^ 1;
    char* cur = smem + (kb & 1) * 16384;

    if (kb < 7) {
      // stage B(kb+1) first (oldest), fence, then A(kb+1) prefetch.
      stage_b(kb + 1, smem + ((kb + 1) & 1) * 16384, wv, lane);
      asm volatile("" ::: "memory");
#pragma unroll
      for (int fm = 0; fm < 2; fm++) {
        const float* p = zrow[fm] + (kb + 1) * 32;
        a0[nA][fm] = *(const float4*)(p);
        a1[nA][fm] = *(const float4*)(p + 4);
      }
    }

    // convert current A fp32 -> fp16 frags (16 v_cvt); compiler inserts
    // the counted vmcnt wait for exactly these loads.
    half8 af[2];
#pragma unroll
    for (int fm = 0; fm < 2; fm++) {
      af[fm][0] = (_Float16)a0[cA][fm].x; af[fm][1] = (_Float16)a0[cA][fm].y;
      af[fm][2] = (_Float16)a0[cA][fm].z; af[fm][3] = (_Float16)a0[cA][fm].w;
      af[fm][4] = (_Float16)a1[cA][fm].x; af[fm][5] = (_Float16)a1[cA][fm].y;
      af[fm][6] = (_Float16)a1[cA][fm].z; af[fm][7] = (_Float16)a1[cA][fm].w;
    }

    const half8* buf = (const half8*)cur;
#pragma unroll
    for (int fn = 0; fn < 8; fn++) {
      int fi = (nh * 128 + fn * 16 + fr) * 4 + qd;   // contiguous 1KB/wave
      half8 bf = buf[fi];
#pragma unroll
      for (int fm = 0; fm < 2; fm++)
        acc[fm][fn] = __builtin_amdgcn_mfma_f32_16x16x32_f16(af[fm], bf, acc[fm][fn], 0, 0, 0);
    }

    // Counted wait (NOT a drain): stage(kb+1) retired, A(kb+1) stays in
    // flight across the barrier. Barrier fences cur's ds_reads (consumed
    // by MFMA) before kb+1 overwrites cur via stage_b(kb+2).
    if (kb < 7) asm volatile("s_waitcnt vmcnt(4)" ::: "memory");
    else        asm volatile("s_waitcnt vmcnt(0)" ::: "memory");
    __builtin_amdgcn_s_barrier();
  }

  // Epilogue: per-wave 16x136-half LDS tile (272B stride: 2-way max, free),
  // reused for both m-frags (same-wave LDS ordering; verified R4-R12).
  __half* et = (__half*)(smem + wv * 4352);
  float bias[8];
#pragma unroll
  for (int fn = 0; fn < 8; fn++) bias[fn] = b[nh * 128 + fn * 16 + fr];

#pragma unroll
  for (int fm = 0; fm < 2; fm++) {
#pragma unroll
    for (int fn = 0; fn < 8; fn++)
#pragma unroll
      for (int r = 0; r < 4; r++)
        et[(qd * 4 + r) * 136 + fn * 16 + fr] = __float2half(acc[fm][fn][r] + bias[fn]);
#pragma unroll
    for (int p = 0; p < 4; p++) {
      int idx = p * 64 + lane;        // 0..255
      int rr = idx >> 4;              // 0..15
      int cc = idx & 15;              // 16B chunk within 256B row-half
      float4 v = *(const float4*)(et + rr * 136 + cc * 8);
      int row = row0 + fm * 16 + rr;
      if (row < nrows)
        *(float4*)(h + (size_t)row * D_DIM + nh * 128 + cc * 8) = v;
    }
  }
}

// 1 wave per 8 edges; per edge ONE 1KB load instr: lanes 0-31 cover the
// 512B src row, lanes 32-63 the dst row. Pair via shfl_xor(32), butterfly.
__global__ __launch_bounds__(256) void edge_dot_kernel(
    const int* __restrict__ ei, const __half* __restrict__ h,
    float* __restrict__ out, int E) {
  int wid = (blockIdx.x * blockDim.x + threadIdx.x) >> 6;
  int lane = threadIdx.x & 63;
  int ebase = wid * 8;
  if (ebase >= E) return;
  const int half = lane >> 5;      // 0=src row, 1=dst row
  const int off = lane & 31;       // float4 chunk within the 512B row

  float4 v[8];
#pragma unroll
  for (int q = 0; q < 8; q++) {
    int e = ebase + q;
    e = e < E ? e : (E - 1);
    int node = half ? ei[E + e] : ei[e];   // uniform per 32-lane half
    v[q] = *(const float4*)((const __half*)h + (size_t)node * D_DIM + off * 8);
  }

  float res = 0.f;
#pragma unroll
  for (int q = 0; q < 8; q++) {
    float4 w;
    w.x = __shfl_xor(v[q].x, 32);
    w.y = __shfl_xor(v[q].y, 32);
    w.z = __shfl_xor(v[q].z, 32);
    w.w = __shfl_xor(v[q].w, 32);
    const __half2* a2 = (const __half2*)&v[q];
    const __half2* b2 = (const __half2*)&w;
    float part = 0.f;
#pragma unroll
    for (int j = 0; j < 4; j++) {
      float2 fa = __half22float2(a2[j]);
      float2 fb = __half22float2(b2[j]);
      part += fa.x * fb.x + fa.y * fb.y;
    }
#pragma unroll
    for (int m = 1; m <= 16; m <<= 1) part += __shfl_xor(part, m);
    res = (lane == q) ? part : res;    // lanes 0..7 collect the 8 results
  }
  if (lane < 8) {
    int e = ebase + lane;
    if (e < E) out[e] = 1.0f / (1.0f + __expf(-res));
  }
}

extern "C" void kernel_launch(void* const* d_in, const int* in_sizes, int n_in,
                              void* d_out, int out_size, void* d_ws, size_t ws_size,
                              hipStream_t stream) {
  const float* z  = (const float*)d_in[0];
  const int*   ei = (const int*)d_in[1];
  const float* W  = (const float*)d_in[2];
  const float* b  = (const float*)d_in[3];
  float* out = (float*)d_out;
  __half* h  = (__half*)d_ws;   // 100000*256*2 = 51.2 MB scratch

  const int nnodes = in_sizes[0] / D_DIM;
  const int E = in_sizes[1] / 2;

  pack_w_kernel<<<32, 256, 0, stream>>>(W);

  dim3 grid_gemm((nnodes + BM - 1) / BM);
  gemm_mfma_kernel<<<grid_gemm, 512, 0, stream>>>(z, b, h, nnodes);

  int waves = (E + 7) / 8;                        // 1 wave per 8 edges
  dim3 grid_edge(((size_t)waves * 64 + 255) / 256);
  edge_dot_kernel<<<grid_edge, 256, 0, stream>>>(ei, h, out, E);
}

// Round 4
// 218.422 us; speedup vs baseline: 1.0558x; 1.0059x over previous
//
#include <hip/hip_runtime.h>
#include <hip/hip_bf16.h>
#include <hip/hip_fp16.h>
#include <math.h>

// Problem: h = z @ W + b  (z [N,256] fp32, W [256,256] fp32, b [256])
//          out[e] = sigmoid(dot(h[src[e]], h[dst[e]]))  for E edges
// N = 100000, E = 300000, D = 256.
//
// R16: R15's occupancy fix (16x128 wave tile, acc 32 AGPR, ~90 unified
// regs/wave -> ~2 blocks/CU staggered) with R12's bulletproof sync:
// plain __syncthreads() per kb. R15's counted `s_waitcnt vmcnt(2)`
// RACED (tripwire): it assumed FIFO vmcnt retirement across MIXED op
// types (global_load_lds vs global_load_dwordx4); when a stage op
// completes late (cold L2) waves crossed the barrier and read stale
// LDS. Full drain is correct; the drain stall is now hidden by the
// OTHER resident block's waves (the occupancy lever under test).
// BM=64, 512 thr, grid 1563, 2x16KB B dbuf staged via global_load_lds.

#define D_DIM 256
#define BM 64

typedef __attribute__((ext_vector_type(8))) _Float16 half8;
typedef __attribute__((ext_vector_type(4))) float f32x4;

__device__ half8 g_Wf[8 * 256 * 4];   // [kb][n][qd] -> 16B fp16 frag, 128 KB

// 8192 threads: t -> (kb, qd, n), n fastest => coalesced row reads of W.
__global__ __launch_bounds__(256) void pack_w_kernel(const float* __restrict__ W) {
  int t = blockIdx.x * 256 + threadIdx.x;   // 0..8191
  int kb = t >> 10;
  int qd = (t >> 8) & 3;
  int n  = t & 255;
  half8 o;
#pragma unroll
  for (int j = 0; j < 8; j++)
    o[j] = (_Float16)W[(size_t)(kb * 32 + qd * 8 + j) * D_DIM + n];
  g_Wf[(kb * 256 + n) * 4 + qd] = o;
}

// Stage one kb's 16 KB of B frags into an LDS buffer; 8 waves x 2 KB.
__device__ inline void stage_b(int kb, char* buf, int wv, int lane) {
  const char* gsrc = (const char*)g_Wf + (size_t)kb * 16384 + wv * 2048;
  char* ldst = buf + wv * 2048;
#pragma unroll
  for (int i = 0; i < 2; i++) {
    __builtin_amdgcn_global_load_lds(
        (const __attribute__((address_space(1))) void*)(gsrc + i * 1024 + lane * 16),
        (__attribute__((address_space(3))) void*)(ldst + i * 1024),
        16, 0, 0);
  }
}

__global__ __launch_bounds__(512) void gemm_mfma_kernel(
    const float* __restrict__ z, const float* __restrict__ b,
    __half* __restrict__ h, int nrows) {
  // 2x16KB B double-buffer; epilogue tiles (8x4352B=34816B) alias the lot.
  __shared__ char smem[34816];
  const int tid = threadIdx.x;
  const int lane = tid & 63;
  const int wv = tid >> 6;          // 0..7
  const int mg = wv >> 1;           // m-group: rows mg*16 .. +15 (1 frag)
  const int nh = wv & 1;            // n-half: cols nh*128 .. +127
  const int fr = lane & 15;
  const int qd = lane >> 4;
  const int row0 = blockIdx.x * BM + mg * 16;

  f32x4 acc[8];
#pragma unroll
  for (int j = 0; j < 8; j++) acc[j] = (f32x4)0.f;

  int r = row0 + fr;
  r = r < nrows ? r : (nrows - 1);
  const float* zrow = z + (size_t)r * D_DIM + qd * 8;

  // A double-buffer in regs; indices static after full unroll.
  float4 a0[2], a1[2];

  // Prologue: stage B(0) to LDS buf0, load A(0) to regs.
  stage_b(0, smem, wv, lane);
  a0[0] = *(const float4*)(zrow);
  a1[0] = *(const float4*)(zrow + 4);
  __syncthreads();   // drains stage(0); A(0) also drained (full drain, safe)

#pragma unroll
  for (int kb = 0; kb < 8; kb++) {
    const int cA = kb & 1;          // static after unroll
    const int nA = cA ^ 1;
    char* cur = smem + (kb & 1) * 16384;

    if (kb < 7) {
      // issue stage B(kb+1) and A(kb+1) prefetch; they overlap the MFMA
      // block below and are drained by the end-of-iteration barrier.
      stage_b(kb + 1, smem + ((kb + 1) & 1) * 16384, wv, lane);
      const float* p = zrow + (kb + 1) * 32;
      a0[nA] = *(const float4*)(p);
      a1[nA] = *(const float4*)(p + 4);
    }

    // convert current A fp32 -> fp16 frag (8 v_cvt)
    half8 af;
    af[0] = (_Float16)a0[cA].x; af[1] = (_Float16)a0[cA].y;
    af[2] = (_Float16)a0[cA].z; af[3] = (_Float16)a0[cA].w;
    af[4] = (_Float16)a1[cA].x; af[5] = (_Float16)a1[cA].y;
    af[6] = (_Float16)a1[cA].z; af[7] = (_Float16)a1[cA].w;

    const half8* buf = (const half8*)cur;
#pragma unroll
    for (int fn = 0; fn < 8; fn++) {
      int fi = (nh * 128 + fn * 16 + fr) * 4 + qd;   // contiguous 1KB/wave
      half8 bf = buf[fi];
      acc[fn] = __builtin_amdgcn_mfma_f32_16x16x32_f16(af, bf, acc[fn], 0, 0, 0);
    }

    // Full drain + barrier: stage(kb+1) retired and visible; cur's reads
    // fenced before kb+1's stage_b(kb+2) overwrites cur. Drain stall is
    // covered by the other resident block(s) on this CU.
    __syncthreads();
  }

  // Epilogue: per-wave 16x136-half LDS tile (272B stride: 2-way max, free).
  __half* et = (__half*)(smem + wv * 4352);
  float bias[8];
#pragma unroll
  for (int fn = 0; fn < 8; fn++) bias[fn] = b[nh * 128 + fn * 16 + fr];

#pragma unroll
  for (int fn = 0; fn < 8; fn++)
#pragma unroll
    for (int rr = 0; rr < 4; rr++)
      et[(qd * 4 + rr) * 136 + fn * 16 + fr] = __float2half(acc[fn][rr] + bias[fn]);
#pragma unroll
  for (int p = 0; p < 4; p++) {
    int idx = p * 64 + lane;        // 0..255
    int rr = idx >> 4;              // 0..15
    int cc = idx & 15;              // 16B chunk within 256B row-half
    float4 v = *(const float4*)(et + rr * 136 + cc * 8);
    int row = row0 + rr;
    if (row < nrows)
      *(float4*)(h + (size_t)row * D_DIM + nh * 128 + cc * 8) = v;
  }
}

// 1 wave per 8 edges; per edge ONE 1KB load instr: lanes 0-31 cover the
// 512B src row, lanes 32-63 the dst row. Pair via shfl_xor(32), butterfly.
__global__ __launch_bounds__(256) void edge_dot_kernel(
    const int* __restrict__ ei, const __half* __restrict__ h,
    float* __restrict__ out, int E) {
  int wid = (blockIdx.x * blockDim.x + threadIdx.x) >> 6;
  int lane = threadIdx.x & 63;
  int ebase = wid * 8;
  if (ebase >= E) return;
  const int half = lane >> 5;      // 0=src row, 1=dst row
  const int off = lane & 31;       // float4 chunk within the 512B row

  float4 v[8];
#pragma unroll
  for (int q = 0; q < 8; q++) {
    int e = ebase + q;
    e = e < E ? e : (E - 1);
    int node = half ? ei[E + e] : ei[e];   // uniform per 32-lane half
    v[q] = *(const float4*)((const __half*)h + (size_t)node * D_DIM + off * 8);
  }

  float res = 0.f;
#pragma unroll
  for (int q = 0; q < 8; q++) {
    float4 w;
    w.x = __shfl_xor(v[q].x, 32);
    w.y = __shfl_xor(v[q].y, 32);
    w.z = __shfl_xor(v[q].z, 32);
    w.w = __shfl_xor(v[q].w, 32);
    const __half2* a2 = (const __half2*)&v[q];
    const __half2* b2 = (const __half2*)&w;
    float part = 0.f;
#pragma unroll
    for (int j = 0; j < 4; j++) {
      float2 fa = __half22float2(a2[j]);
      float2 fb = __half22float2(b2[j]);
      part += fa.x * fb.x + fa.y * fb.y;
    }
#pragma unroll
    for (int m = 1; m <= 16; m <<= 1) part += __shfl_xor(part, m);
    res = (lane == q) ? part : res;    // lanes 0..7 collect the 8 results
  }
  if (lane < 8) {
    int e = ebase + lane;
    if (e < E) out[e] = 1.0f / (1.0f + __expf(-res));
  }
}

extern "C" void kernel_launch(void* const* d_in, const int* in_sizes, int n_in,
                              void* d_out, int out_size, void* d_ws, size_t ws_size,
                              hipStream_t stream) {
  const float* z  = (const float*)d_in[0];
  const int*   ei = (const int*)d_in[1];
  const float* W  = (const float*)d_in[2];
  const float* b  = (const float*)d_in[3];
  float* out = (float*)d_out;
  __half* h  = (__half*)d_ws;   // 100000*256*2 = 51.2 MB scratch

  const int nnodes = in_sizes[0] / D_DIM;
  const int E = in_sizes[1] / 2;

  pack_w_kernel<<<32, 256, 0, stream>>>(W);

  dim3 grid_gemm((nnodes + BM - 1) / BM);
  gemm_mfma_kernel<<<grid_gemm, 512, 0, stream>>>(z, b, h, nnodes);

  int waves = (E + 7) / 8;                        // 1 wave per 8 edges
  dim3 grid_edge(((size_t)waves * 64 + 255) / 256);
  edge_dot_kernel<<<grid_edge, 256, 0, stream>>>(ei, h, out, E);
}

// Round 5
// 215.376 us; speedup vs baseline: 1.0707x; 1.0141x over previous
//
#include <hip/hip_runtime.h>
#include <hip/hip_bf16.h>
#include <hip/hip_fp16.h>
#include <math.h>

// Problem: h = z @ W + b  (z [N,256] fp32, W [256,256] fp32, b [256])
//          out[e] = sigmoid(dot(h[src[e]], h[dst[e]]))  for E edges
// N = 100000, E = 300000, D = 256.
//
// R17: persistent-block GEMM attacking the measured 64B-request ceiling
// (~120 req/ns invariant across R12/R13/R16; 7-9M requests -> ~63us).
// 256 blocks x 512 thr; each block stages ALL of B (128KB fp16 frags)
// into LDS ONCE (B traffic 200MB -> 32MB), then 8 independent waves
// grid-stride over 16-row strips of z with NO barriers in the loop
// (one __syncthreads total). Requests: 7.2M -> 2.9M => ~24us floor.
// New g_Wf layout [kb][fn][qd][fr]: B ds_read is lane*16B contiguous ->
// conflict-free (was 8-way, 3.4M conflict cycles). A: all 16 float4 of
// a strip issued up front, pinned by asm memory clobber (R13: without
// pinning the compiler sinks loads to uses and serializes).

#define D_DIM 256

typedef __attribute__((ext_vector_type(8))) _Float16 half8;
typedef __attribute__((ext_vector_type(4))) float f32x4;

__device__ half8 g_Wf[8 * 256 * 4];   // [kb][fn][qd][fr], 128 KB

// 8192 threads: t -> (kb, qd, n), n fastest => coalesced row reads of W.
// frag(n = fn*16+fr, qd)[j] = W[(kb*32 + qd*8 + j)*256 + n]
__global__ __launch_bounds__(256) void pack_w_kernel(const float* __restrict__ W) {
  int t = blockIdx.x * 256 + threadIdx.x;   // 0..8191
  int kb = t >> 10;
  int qd = (t >> 8) & 3;
  int n  = t & 255;
  int fn = n >> 4;
  int fr = n & 15;
  half8 o;
#pragma unroll
  for (int j = 0; j < 8; j++)
    o[j] = (_Float16)W[(size_t)(kb * 32 + qd * 8 + j) * D_DIM + n];
  g_Wf[kb * 1024 + fn * 64 + qd * 16 + fr] = o;
}

__global__ __launch_bounds__(512, 2) void gemm_mfma_kernel(
    const float* __restrict__ z, const float* __restrict__ b,
    __half* __restrict__ h, int nrows) {
  // 128KB resident B + 8 x 2176B per-wave epilogue tiles = 145.4KB
  __shared__ char smem[131072 + 8 * 2176];
  const int tid = threadIdx.x;
  const int lane = tid & 63;
  const int wv = tid >> 6;          // 0..7
  const int fr = lane & 15;
  const int qd = lane >> 4;

  // ---- one-time B stage: linear 128KB copy, 16 rounds x (8 waves x 1KB)
  {
    const char* gsrc = (const char*)g_Wf;
#pragma unroll
    for (int rnd = 0; rnd < 16; rnd++) {
      int off = rnd * 8192 + wv * 1024;
      __builtin_amdgcn_global_load_lds(
          (const __attribute__((address_space(1))) void*)(gsrc + off + lane * 16),
          (__attribute__((address_space(3))) void*)(smem + off),
          16, 0, 0);
    }
  }
  // bias into regs (independent of LDS)
  float bias[16];
#pragma unroll
  for (int fn = 0; fn < 16; fn++) bias[fn] = b[fn * 16 + fr];

  __syncthreads();   // the ONLY barrier: B resident & read-only hereafter

  const half8* bw = (const half8*)smem;          // [kb*1024 + fn*64 + lane]
  __half* et = (__half*)(smem + 131072 + wv * 2176);  // 8 x 136 halves

  const int gw = blockIdx.x * 8 + wv;            // 0..2047
  const int nstrips = (nrows + 15) >> 4;         // 6250

#pragma unroll 1
  for (int s = gw; s < nstrips; s += 2048) {
    int r = s * 16 + fr;
    r = r < nrows ? r : (nrows - 1);
    const float* zr = z + (size_t)r * D_DIM + qd * 8;

    // issue ALL 16 A loads for this strip (16 rows x full K), then pin.
    float4 a0[8], a1[8];
#pragma unroll
    for (int kb = 0; kb < 8; kb++) {
      a0[kb] = *(const float4*)(zr + kb * 32);
      a1[kb] = *(const float4*)(zr + kb * 32 + 4);
    }
    asm volatile("" ::: "memory");   // pin: loads issue before compute

    f32x4 acc[16];
#pragma unroll
    for (int fn = 0; fn < 16; fn++) acc[fn] = (f32x4)0.f;

#pragma unroll
    for (int kb = 0; kb < 8; kb++) {
      half8 af;
      af[0] = (_Float16)a0[kb].x; af[1] = (_Float16)a0[kb].y;
      af[2] = (_Float16)a0[kb].z; af[3] = (_Float16)a0[kb].w;
      af[4] = (_Float16)a1[kb].x; af[5] = (_Float16)a1[kb].y;
      af[6] = (_Float16)a1[kb].z; af[7] = (_Float16)a1[kb].w;
#pragma unroll
      for (int fn = 0; fn < 16; fn++) {
        half8 bf = bw[kb * 1024 + fn * 64 + lane];   // contiguous 1KB/wave
        acc[fn] = __builtin_amdgcn_mfma_f32_16x16x32_f16(af, bf, acc[fn], 0, 0, 0);
      }
    }

    // epilogue: 4 passes (row-half ph x col-half ch) through the 8x136
    // wave-private tile (272B stride; same-wave LDS ordering).
#pragma unroll
    for (int ph = 0; ph < 2; ph++) {
#pragma unroll
      for (int ch = 0; ch < 2; ch++) {
        if ((qd >> 1) == ph) {
#pragma unroll
          for (int f2 = 0; f2 < 8; f2++) {
            int fn = ch * 8 + f2;
#pragma unroll
            for (int rr = 0; rr < 4; rr++)
              et[((qd & 1) * 4 + rr) * 136 + f2 * 16 + fr] =
                  __float2half(acc[fn][rr] + bias[fn]);
          }
        }
#pragma unroll
        for (int p = 0; p < 2; p++) {
          int idx = p * 64 + lane;     // 0..127
          int rr = idx >> 4;           // 0..7
          int cc = idx & 15;           // 16B chunk within 128-col half
          float4 v = *(const float4*)(et + rr * 136 + cc * 8);
          int row = s * 16 + ph * 8 + rr;
          if (row < nrows)
            *(float4*)(h + (size_t)row * D_DIM + ch * 128 + cc * 8) = v;
        }
      }
    }
  }
}

// 1 wave per 8 edges; per edge ONE 1KB load instr: lanes 0-31 cover the
// 512B src row, lanes 32-63 the dst row. Pair via shfl_xor(32), butterfly.
__global__ __launch_bounds__(256) void edge_dot_kernel(
    const int* __restrict__ ei, const __half* __restrict__ h,
    float* __restrict__ out, int E) {
  int wid = (blockIdx.x * blockDim.x + threadIdx.x) >> 6;
  int lane = threadIdx.x & 63;
  int ebase = wid * 8;
  if (ebase >= E) return;
  const int half = lane >> 5;      // 0=src row, 1=dst row
  const int off = lane & 31;       // float4 chunk within the 512B row

  float4 v[8];
#pragma unroll
  for (int q = 0; q < 8; q++) {
    int e = ebase + q;
    e = e < E ? e : (E - 1);
    int node = half ? ei[E + e] : ei[e];   // uniform per 32-lane half
    v[q] = *(const float4*)((const __half*)h + (size_t)node * D_DIM + off * 8);
  }

  float res = 0.f;
#pragma unroll
  for (int q = 0; q < 8; q++) {
    float4 w;
    w.x = __shfl_xor(v[q].x, 32);
    w.y = __shfl_xor(v[q].y, 32);
    w.z = __shfl_xor(v[q].z, 32);
    w.w = __shfl_xor(v[q].w, 32);
    const __half2* a2 = (const __half2*)&v[q];
    const __half2* b2 = (const __half2*)&w;
    float part = 0.f;
#pragma unroll
    for (int j = 0; j < 4; j++) {
      float2 fa = __half22float2(a2[j]);
      float2 fb = __half22float2(b2[j]);
      part += fa.x * fb.x + fa.y * fb.y;
    }
#pragma unroll
    for (int m = 1; m <= 16; m <<= 1) part += __shfl_xor(part, m);
    res = (lane == q) ? part : res;    // lanes 0..7 collect the 8 results
  }
  if (lane < 8) {
    int e = ebase + lane;
    if (e < E) out[e] = 1.0f / (1.0f + __expf(-res));
  }
}

extern "C" void kernel_launch(void* const* d_in, const int* in_sizes, int n_in,
                              void* d_out, int out_size, void* d_ws, size_t ws_size,
                              hipStream_t stream) {
  const float* z  = (const float*)d_in[0];
  const int*   ei = (const int*)d_in[1];
  const float* W  = (const float*)d_in[2];
  const float* b  = (const float*)d_in[3];
  float* out = (float*)d_out;
  __half* h  = (__half*)d_ws;   // 100000*256*2 = 51.2 MB scratch

  const int nnodes = in_sizes[0] / D_DIM;
  const int E = in_sizes[1] / 2;

  pack_w_kernel<<<32, 256, 0, stream>>>(W);

  gemm_mfma_kernel<<<256, 512, 0, stream>>>(z, b, h, nnodes);

  int waves = (E + 7) / 8;                        // 1 wave per 8 edges
  dim3 grid_edge(((size_t)waves * 64 + 255) / 256);
  edge_dot_kernel<<<grid_edge, 256, 0, stream>>>(ei, h, out, E);
}